// Round 1
// baseline (578.559 us; speedup 1.0000x reference)
//
#include <hip/hip_runtime.h>

// ---------- types / helpers ----------
typedef __attribute__((ext_vector_type(8))) short bfrag;   // 8 bf16 (4 VGPRs) MFMA operand
typedef __attribute__((ext_vector_type(4))) float f32x4;   // MFMA accumulator

__device__ __forceinline__ float bf2f(unsigned short u) {
    union { unsigned u32; float f; } cv; cv.u32 = ((unsigned)u) << 16; return cv.f;
}
__device__ __forceinline__ unsigned short f2bf(float f) {
    union { float f; unsigned u; } cv; cv.f = f;
    unsigned u = cv.u;
    unsigned r = (u + 0x7fffu + ((u >> 16) & 1u)) >> 16;   // round-to-nearest-even
    return (unsigned short)r;
}
__device__ __forceinline__ void gll16(const void* g, void* l) {
    __builtin_amdgcn_global_load_lds(
        (const __attribute__((address_space(1))) unsigned int*)g,
        (__attribute__((address_space(3))) unsigned int*)l, 16, 0, 0);
}

// ---------- weight transpose + pad + bf16 convert:  W[R][Cn] f32 -> WT[Cn][Kp] bf16 ----------
__global__ void transpose_pad(const float* __restrict__ W, unsigned short* __restrict__ WT,
                              int R, int Cn, int Kp) {
    __shared__ unsigned short tile[32][33];
    int r0 = blockIdx.x * 32, c0 = blockIdx.y * 32;
#pragma unroll
    for (int j = 0; j < 4; j++) {
        int r = r0 + threadIdx.y + j * 8;
        int c = c0 + threadIdx.x;
        float v = (r < R) ? W[(size_t)r * Cn + c] : 0.f;
        tile[threadIdx.y + j * 8][threadIdx.x] = f2bf(v);
    }
    __syncthreads();
#pragma unroll
    for (int j = 0; j < 4; j++) {
        int c = c0 + threadIdx.y + j * 8;
        WT[(size_t)c * Kp + r0 + threadIdx.x] = tile[threadIdx.x][threadIdx.y + j * 8];
    }
}

// ---------- gather-sum + concat -> xb chunk [nb*128][448] bf16 (zero-padded) ----------
__global__ void gather_concat(const float* __restrict__ atom_out, const float* __restrict__ f_atoms,
                              const int* __restrict__ a2a, unsigned short* __restrict__ xb,
                              int row0, int n_real) {
    int r = row0 + blockIdx.x;
    int t = threadIdx.x;
    unsigned short* xrow = xb + (size_t)blockIdx.x * 448;
    if (r >= n_real) {
        for (int c = t; c < 448; c += 256) xrow[c] = 0;
        return;
    }
    __shared__ int nb[10];
    if (t < 10) nb[t] = a2a[(size_t)r * 10 + t];
    __syncthreads();
    float acc = 0.f;
#pragma unroll
    for (int j = 0; j < 10; j++) acc += atom_out[(size_t)nb[j] * 256 + t];
    xrow[151 + t] = f2bf(acc);
    if (t < 151) xrow[t] = f2bf(f_atoms[(size_t)r * 151 + t]);
    if (t < 41) xrow[407 + t] = 0;
}

// ---------- bf16 MFMA GEMM, B given transposed:  C[M][N] = A[M][K] * BT[N][K]^T (+bias, relu) ----------
// 128x128 tile, BK=64, 4 waves (2x2), each wave 64x64 via 4x4 frags of 16x16x32.
template <int RELU>
__global__ __launch_bounds__(256) void gemm_bt(const unsigned short* __restrict__ A,
                                               const unsigned short* __restrict__ BT,
                                               const float* __restrict__ bias,
                                               unsigned short* __restrict__ C, int N, int K) {
    __shared__ __align__(16) unsigned short As[128 * 64];
    __shared__ __align__(16) unsigned short Bs[128 * 64];
    const int t = threadIdx.x;
    const int lane = t & 63, w = t >> 6;
    const int wr = w >> 1, wc = w & 1;
    const int bm = blockIdx.x * 128, bn = blockIdx.y * 128;

    f32x4 acc[4][4] = {};

    const unsigned short* Ag = A + (size_t)(bm + (t >> 3)) * K + (t & 7) * 8;
    const unsigned short* Bg = BT + (size_t)(bn + (t >> 3)) * K + (t & 7) * 8;
    unsigned short* Al = &As[t * 8];
    unsigned short* Bl = &Bs[t * 8];

    const int la = lane & 15, lb = (lane >> 4) * 8;

    for (int k0 = 0; k0 < K; k0 += 64) {
        __syncthreads();   // previous compute done before overwriting LDS
#pragma unroll
        for (int p = 0; p < 4; p++) gll16(Ag + (size_t)(p * 32) * K + k0, Al + p * 2048);
#pragma unroll
        for (int p = 0; p < 4; p++) gll16(Bg + (size_t)(p * 32) * K + k0, Bl + p * 2048);
        asm volatile("s_waitcnt vmcnt(0)" ::: "memory");
        __syncthreads();
#pragma unroll
        for (int kk = 0; kk < 2; kk++) {
            bfrag a[4], b[4];
#pragma unroll
            for (int i = 0; i < 4; i++)
                a[i] = *reinterpret_cast<const bfrag*>(&As[(wr * 64 + i * 16 + la) * 64 + kk * 32 + lb]);
#pragma unroll
            for (int i = 0; i < 4; i++)
                b[i] = *reinterpret_cast<const bfrag*>(&Bs[(wc * 64 + i * 16 + la) * 64 + kk * 32 + lb]);
#pragma unroll
            for (int i = 0; i < 4; i++)
#pragma unroll
                for (int j = 0; j < 4; j++)
                    acc[i][j] = __builtin_amdgcn_mfma_f32_16x16x32_bf16(a[i], b[j], acc[i][j], 0, 0, 0);
        }
    }

#pragma unroll
    for (int j = 0; j < 4; j++) {
        int col = bn + wc * 64 + j * 16 + la;
        float bv = bias[col];
#pragma unroll
        for (int i = 0; i < 4; i++) {
            int rbase = bm + wr * 64 + i * 16 + (lane >> 4) * 4;
#pragma unroll
            for (int r = 0; r < 4; r++) {
                float v = acc[i][j][r] + bv;
                if (RELU) v = fmaxf(v, 0.f);
                C[(size_t)(rbase + r) * N + col] = f2bf(v);
            }
        }
    }
}

// ---------- in-place LayerNorm over 256 cols, one wave per row ----------
__global__ void layernorm_inplace(unsigned short* __restrict__ h, const float* __restrict__ g,
                                  const float* __restrict__ b) {
    int row = blockIdx.x * 4 + (threadIdx.x >> 6);
    int lane = threadIdx.x & 63;
    unsigned short* hp = h + (size_t)row * 256 + lane * 4;
    ushort4 u = *reinterpret_cast<const ushort4*>(hp);
    float v0 = bf2f(u.x), v1 = bf2f(u.y), v2 = bf2f(u.z), v3 = bf2f(u.w);
    float s = v0 + v1 + v2 + v3;
    float q = v0 * v0 + v1 * v1 + v2 * v2 + v3 * v3;
#pragma unroll
    for (int off = 32; off; off >>= 1) {
        s += __shfl_xor(s, off);
        q += __shfl_xor(q, off);
    }
    float mean = s * (1.f / 256.f);
    float var = q * (1.f / 256.f) - mean * mean;
    float rs = rsqrtf(var + 1e-5f);
    float4 gv = *reinterpret_cast<const float4*>(g + lane * 4);
    float4 bv = *reinterpret_cast<const float4*>(b + lane * 4);
    ushort4 o;
    o.x = f2bf((v0 - mean) * rs * gv.x + bv.x);
    o.y = f2bf((v1 - mean) * rs * gv.y + bv.y);
    o.z = f2bf((v2 - mean) * rs * gv.z + bv.z);
    o.w = f2bf((v3 - mean) * rs * gv.w + bv.w);
    *reinterpret_cast<ushort4*>(hp) = o;
}

// ---------- segment mean + concat features -> mol [2560][512] bf16 ----------
__global__ void seg_mean_concat(const unsigned short* __restrict__ h, const int* __restrict__ a_scope,
                                const float* __restrict__ feats, unsigned short* __restrict__ mol,
                                int n_mols) {
    int m = blockIdx.x, t = threadIdx.x;
    unsigned short* mrow = mol + (size_t)m * 512;
    if (m >= n_mols) {
        mrow[t] = 0;
        mrow[256 + t] = 0;
        return;
    }
    int start = a_scope[2 * m], size = a_scope[2 * m + 1];
    float acc = 0.f;
    for (int j = 0; j < size; j++) acc += bf2f(h[(size_t)(start + j) * 256 + t]);
    mrow[t] = f2bf(acc / (float)size);
    int c = 256 + t;
    float fv = (c < 456) ? feats[(size_t)m * 200 + (c - 256)] : 0.f;
    mrow[c] = f2bf(fv);
}

// ---------- final tiny FFN layer: out[2500][12] = relu_m1[2500][1024] @ Wm2 + bm2 ----------
__global__ void ffn2(const unsigned short* __restrict__ m1, const float* __restrict__ Wm2,
                     const float* __restrict__ bm2, float* __restrict__ out, int n_mols) {
    int wid = blockIdx.x * 4 + (threadIdx.x >> 6);
    if (wid >= n_mols) return;
    int lane = threadIdx.x & 63;
    float acc[12] = {};
    const unsigned short* row = m1 + (size_t)wid * 1024;
#pragma unroll 4
    for (int i = 0; i < 16; i++) {
        int k = i * 64 + lane;
        float v = bf2f(row[k]);
        const float* wr_ = Wm2 + (size_t)k * 12;
#pragma unroll
        for (int tsk = 0; tsk < 12; tsk++) acc[tsk] += v * wr_[tsk];
    }
#pragma unroll
    for (int tsk = 0; tsk < 12; tsk++) {
        float sv = acc[tsk];
#pragma unroll
        for (int off = 32; off; off >>= 1) sv += __shfl_xor(sv, off);
        if (lane == 0) out[(size_t)wid * 12 + tsk] = sv + bm2[tsk];
    }
}

// ---------- launch ----------
extern "C" void kernel_launch(void* const* d_in, const int* in_sizes, int n_in,
                              void* d_out, int out_size, void* d_ws, size_t ws_size,
                              hipStream_t stream) {
    const float* atom_output = (const float*)d_in[0];
    const float* f_atoms     = (const float*)d_in[1];
    const int*   a2a         = (const int*)d_in[2];
    const int*   a_scope     = (const int*)d_in[3];
    const float* feats       = (const float*)d_in[4];
    const float* W1  = (const float*)d_in[5];
    const float* b1  = (const float*)d_in[6];
    const float* W2  = (const float*)d_in[7];
    const float* b2  = (const float*)d_in[8];
    const float* ln_g = (const float*)d_in[9];
    const float* ln_b = (const float*)d_in[10];
    const float* Wm1 = (const float*)d_in[11];
    const float* bm1 = (const float*)d_in[12];
    const float* Wm2 = (const float*)d_in[13];
    const float* bm2 = (const float*)d_in[14];
    float* out = (float*)d_out;

    char* ws = (char*)d_ws;
    size_t off = 0;
    auto alloc = [&](size_t bytes) {
        void* p = ws + off;
        off += (bytes + 255) & ~(size_t)255;
        return p;
    };
    // chunked over M: 4 chunks of {196,196,196,194} row-blocks of 128
    unsigned short* xbc   = (unsigned short*)alloc((size_t)25088 * 448 * 2);   // 22.5 MB
    unsigned short* h1    = (unsigned short*)alloc((size_t)25088 * 1024 * 2);  // 51.4 MB
    unsigned short* h     = (unsigned short*)alloc((size_t)100096 * 256 * 2);  // 51.2 MB
    unsigned short* mol   = (unsigned short*)alloc((size_t)2560 * 512 * 2);
    unsigned short* m1b   = (unsigned short*)alloc((size_t)2560 * 1024 * 2);
    unsigned short* W1bT  = (unsigned short*)alloc((size_t)1024 * 448 * 2);
    unsigned short* W2bT  = (unsigned short*)alloc((size_t)256 * 1024 * 2);
    unsigned short* Wm1bT = (unsigned short*)alloc((size_t)1024 * 512 * 2);

    // weight prep: f32 [R][Cn] -> bf16 [Cn][Kp], K zero-padded
    transpose_pad<<<dim3(14, 32), dim3(32, 8), 0, stream>>>(W1, W1bT, 407, 1024, 448);
    transpose_pad<<<dim3(32, 8),  dim3(32, 8), 0, stream>>>(W2, W2bT, 1024, 256, 1024);
    transpose_pad<<<dim3(16, 32), dim3(32, 8), 0, stream>>>(Wm1, Wm1bT, 456, 1024, 512);

    const int row0s[4] = {0, 25088, 50176, 75264};
    const int nbs[4]   = {196, 196, 196, 194};
    for (int c = 0; c < 4; c++) {
        int row0 = row0s[c], nb = nbs[c];
        gather_concat<<<nb * 128, 256, 0, stream>>>(atom_output, f_atoms, a2a, xbc, row0, 100000);
        // h1 = relu(x @ W1 + b1)  : M=nb*128, N=1024, K=448
        gemm_bt<1><<<dim3(nb, 8), 256, 0, stream>>>(xbc, W1bT, b1, h1, 1024, 448);
        // h_pre = h1 @ W2 + b2    : M=nb*128, N=256, K=1024
        gemm_bt<0><<<dim3(nb, 2), 256, 0, stream>>>(h1, W2bT, b2, h + (size_t)row0 * 256, 256, 1024);
    }
    layernorm_inplace<<<25000, 256, 0, stream>>>(h, ln_g, ln_b);
    seg_mean_concat<<<2560, 256, 0, stream>>>(h, a_scope, feats, mol, 2500);
    // m1 = relu(mol @ Wm1 + bm1) : M=2560, N=1024, K=512
    gemm_bt<1><<<dim3(20, 8), 256, 0, stream>>>(mol, Wm1bT, bm1, m1b, 1024, 512);
    ffn2<<<625, 256, 0, stream>>>(m1b, Wm2, bm2, out, 2500);
}

// Round 2
// 510.451 us; speedup vs baseline: 1.1334x; 1.1334x over previous
//
#include <hip/hip_runtime.h>

// ---------- types / helpers ----------
typedef __attribute__((ext_vector_type(8))) short bfrag;   // 8 bf16 (4 VGPRs) MFMA operand
typedef __attribute__((ext_vector_type(4))) float f32x4;   // MFMA accumulator

__device__ __forceinline__ float bf2f(unsigned short u) {
    union { unsigned u32; float f; } cv; cv.u32 = ((unsigned)u) << 16; return cv.f;
}
__device__ __forceinline__ unsigned short f2bf(float f) {
    union { float f; unsigned u; } cv; cv.f = f;
    unsigned u = cv.u;
    unsigned r = (u + 0x7fffu + ((u >> 16) & 1u)) >> 16;   // round-to-nearest-even
    return (unsigned short)r;
}
__device__ __forceinline__ float ld_elem(float v) { return v; }
__device__ __forceinline__ float ld_elem(unsigned short v) { return bf2f(v); }
__device__ __forceinline__ void gll16(const void* g, void* l) {
    __builtin_amdgcn_global_load_lds(
        (const __attribute__((address_space(1))) unsigned int*)g,
        (__attribute__((address_space(3))) unsigned int*)l, 16, 0, 0);
}

// ---------- f32 -> bf16 bulk convert (n multiple of 2048) ----------
__global__ void to_bf16(const float* __restrict__ src, unsigned short* __restrict__ dst, size_t n) {
    size_t i = ((size_t)blockIdx.x * 256 + threadIdx.x) * 8;
    if (i >= n) return;
    float4 a = *reinterpret_cast<const float4*>(src + i);
    float4 b = *reinterpret_cast<const float4*>(src + i + 4);
    ushort4 o0 = {f2bf(a.x), f2bf(a.y), f2bf(a.z), f2bf(a.w)};
    ushort4 o1 = {f2bf(b.x), f2bf(b.y), f2bf(b.z), f2bf(b.w)};
    *reinterpret_cast<ushort4*>(dst + i) = o0;
    *reinterpret_cast<ushort4*>(dst + i + 4) = o1;
}

// ---------- weight transpose + pad + bf16 convert:  W[R][Cn] f32 -> WT[Cn][Kp] bf16 ----------
__global__ void transpose_pad(const float* __restrict__ W, unsigned short* __restrict__ WT,
                              int R, int Cn, int Kp) {
    __shared__ unsigned short tile[32][33];
    int r0 = blockIdx.x * 32, c0 = blockIdx.y * 32;
#pragma unroll
    for (int j = 0; j < 4; j++) {
        int r = r0 + threadIdx.y + j * 8;
        int c = c0 + threadIdx.x;
        float v = (r < R) ? W[(size_t)r * Cn + c] : 0.f;
        tile[threadIdx.y + j * 8][threadIdx.x] = f2bf(v);
    }
    __syncthreads();
#pragma unroll
    for (int j = 0; j < 4; j++) {
        int c = c0 + threadIdx.y + j * 8;
        WT[(size_t)c * Kp + r0 + threadIdx.x] = tile[threadIdx.x][threadIdx.y + j * 8];
    }
}

// ---------- gather-sum + concat -> xb [nrows][448] bf16 (zero-padded) ----------
template <typename T>
__global__ void gather_concat(const T* __restrict__ atom_src, const float* __restrict__ f_atoms,
                              const int* __restrict__ a2a, unsigned short* __restrict__ xb,
                              int row0, int n_real) {
    int r = row0 + blockIdx.x;
    int t = threadIdx.x;
    unsigned short* xrow = xb + (size_t)blockIdx.x * 448;
    if (r >= n_real) {
        for (int c = t; c < 448; c += 256) xrow[c] = 0;
        return;
    }
    __shared__ int nb[10];
    if (t < 10) nb[t] = a2a[(size_t)r * 10 + t];
    __syncthreads();
    float acc = 0.f;
#pragma unroll
    for (int j = 0; j < 10; j++) acc += ld_elem(atom_src[(size_t)nb[j] * 256 + t]);
    xrow[151 + t] = f2bf(acc);
    if (t < 151) xrow[t] = f2bf(f_atoms[(size_t)r * 151 + t]);
    if (t < 41) xrow[407 + t] = 0;
}

// ---------- bf16 MFMA GEMM, B given transposed:  C[M][N] = A[M][K] * BT[N][K]^T (+bias, relu) ----------
// 128x128 tile, BK=64, 4 waves (2x2). 1-D grid = MB*NB blocks, XCD-swizzled, N-block fastest.
template <int RELU>
__global__ __launch_bounds__(256) void gemm_bt(const unsigned short* __restrict__ A,
                                               const unsigned short* __restrict__ BT,
                                               const float* __restrict__ bias,
                                               unsigned short* __restrict__ C,
                                               int NB, int N, int K) {
    __shared__ __align__(16) unsigned short As[128 * 64];
    __shared__ __align__(16) unsigned short Bs[128 * 64];
    const int t = threadIdx.x;
    const int lane = t & 63, w = t >> 6;
    const int wr = w >> 1, wc = w & 1;

    // bijective XCD swizzle (m204): each XCD gets a contiguous wgid chunk;
    // wgid enumerates N-block fastest so the NB blocks sharing an A-tile co-reside on one XCD.
    const int nwg = gridDim.x;
    const int orig = blockIdx.x;
    const int q = nwg >> 3, r8 = nwg & 7;
    const int xcd = orig & 7, slot = orig >> 3;
    const int wgid = (xcd < r8 ? xcd * (q + 1) : r8 * (q + 1) + (xcd - r8) * q) + slot;
    const int bm = (wgid / NB) * 128, bn = (wgid % NB) * 128;

    f32x4 acc[4][4] = {};

    const unsigned short* Ag = A + (size_t)(bm + (t >> 3)) * K + (t & 7) * 8;
    const unsigned short* Bg = BT + (size_t)(bn + (t >> 3)) * K + (t & 7) * 8;
    unsigned short* Al = &As[t * 8];
    unsigned short* Bl = &Bs[t * 8];

    const int la = lane & 15, lb = (lane >> 4) * 8;

    for (int k0 = 0; k0 < K; k0 += 64) {
        __syncthreads();   // previous compute done before overwriting LDS
#pragma unroll
        for (int p = 0; p < 4; p++) gll16(Ag + (size_t)(p * 32) * K + k0, Al + p * 2048);
#pragma unroll
        for (int p = 0; p < 4; p++) gll16(Bg + (size_t)(p * 32) * K + k0, Bl + p * 2048);
        asm volatile("s_waitcnt vmcnt(0)" ::: "memory");
        __syncthreads();
#pragma unroll
        for (int kk = 0; kk < 2; kk++) {
            bfrag a[4], b[4];
#pragma unroll
            for (int i = 0; i < 4; i++)
                a[i] = *reinterpret_cast<const bfrag*>(&As[(wr * 64 + i * 16 + la) * 64 + kk * 32 + lb]);
#pragma unroll
            for (int i = 0; i < 4; i++)
                b[i] = *reinterpret_cast<const bfrag*>(&Bs[(wc * 64 + i * 16 + la) * 64 + kk * 32 + lb]);
#pragma unroll
            for (int i = 0; i < 4; i++)
#pragma unroll
                for (int j = 0; j < 4; j++)
                    acc[i][j] = __builtin_amdgcn_mfma_f32_16x16x32_bf16(a[i], b[j], acc[i][j], 0, 0, 0);
        }
    }

#pragma unroll
    for (int j = 0; j < 4; j++) {
        int col = bn + wc * 64 + j * 16 + la;
        float bv = bias[col];
#pragma unroll
        for (int i = 0; i < 4; i++) {
            int rbase = bm + wr * 64 + i * 16 + (lane >> 4) * 4;
#pragma unroll
            for (int r = 0; r < 4; r++) {
                float v = acc[i][j][r] + bv;
                if (RELU) v = fmaxf(v, 0.f);
                C[(size_t)(rbase + r) * N + col] = f2bf(v);
            }
        }
    }
}

// ---------- fused LayerNorm + segment-mean + feature concat ----------
// one block (8 waves) per molecule; wave-per-row LN with shfl reduce; LDS partial sums.
__global__ __launch_bounds__(512) void seg_ln_mean(const unsigned short* __restrict__ h,
                                                   const int* __restrict__ a_scope,
                                                   const float* __restrict__ g,
                                                   const float* __restrict__ b,
                                                   const float* __restrict__ feats,
                                                   unsigned short* __restrict__ mol, int n_mols) {
    __shared__ float part[8][256];
    int m = blockIdx.x, t = threadIdx.x;
    unsigned short* mrow = mol + (size_t)m * 512;
    if (m >= n_mols) {
        mrow[t] = 0;   // 512 threads cover the 512-wide padded row
        return;
    }
    int w = t >> 6, lane = t & 63;
    int start = a_scope[2 * m], size = a_scope[2 * m + 1];
    float4 gv = *reinterpret_cast<const float4*>(g + lane * 4);
    float4 bv = *reinterpret_cast<const float4*>(b + lane * 4);
    float a0 = 0.f, a1 = 0.f, a2 = 0.f, a3 = 0.f;
    for (int r = w; r < size; r += 8) {
        const unsigned short* hp = h + (size_t)(start + r) * 256 + lane * 4;
        ushort4 u = *reinterpret_cast<const ushort4*>(hp);
        float v0 = bf2f(u.x), v1 = bf2f(u.y), v2 = bf2f(u.z), v3 = bf2f(u.w);
        float s = v0 + v1 + v2 + v3;
        float q2 = v0 * v0 + v1 * v1 + v2 * v2 + v3 * v3;
#pragma unroll
        for (int off = 32; off; off >>= 1) {
            s += __shfl_xor(s, off);
            q2 += __shfl_xor(q2, off);
        }
        float mean = s * (1.f / 256.f);
        float var = q2 * (1.f / 256.f) - mean * mean;
        float rs = rsqrtf(var + 1e-5f);
        a0 += (v0 - mean) * rs * gv.x + bv.x;
        a1 += (v1 - mean) * rs * gv.y + bv.y;
        a2 += (v2 - mean) * rs * gv.z + bv.z;
        a3 += (v3 - mean) * rs * gv.w + bv.w;
    }
    part[w][lane * 4 + 0] = a0;
    part[w][lane * 4 + 1] = a1;
    part[w][lane * 4 + 2] = a2;
    part[w][lane * 4 + 3] = a3;
    __syncthreads();
    if (t < 256) {
        float sum = 0.f;
#pragma unroll
        for (int i = 0; i < 8; i++) sum += part[i][t];
        mrow[t] = f2bf(sum / (float)size);
    } else {
        int c = t - 256;
        float fv = (c < 200) ? feats[(size_t)m * 200 + c] : 0.f;
        mrow[256 + c] = f2bf(fv);
    }
}

// ---------- final tiny FFN layer: out[2500][12] = relu_m1[2500][1024] @ Wm2 + bm2 ----------
__global__ void ffn2(const unsigned short* __restrict__ m1, const float* __restrict__ Wm2,
                     const float* __restrict__ bm2, float* __restrict__ out, int n_mols) {
    int wid = blockIdx.x * 4 + (threadIdx.x >> 6);
    if (wid >= n_mols) return;
    int lane = threadIdx.x & 63;
    float acc[12] = {};
    const unsigned short* row = m1 + (size_t)wid * 1024;
#pragma unroll 4
    for (int i = 0; i < 16; i++) {
        int k = i * 64 + lane;
        float v = bf2f(row[k]);
        const float* wr_ = Wm2 + (size_t)k * 12;
#pragma unroll
        for (int tsk = 0; tsk < 12; tsk++) acc[tsk] += v * wr_[tsk];
    }
#pragma unroll
    for (int tsk = 0; tsk < 12; tsk++) {
        float sv = acc[tsk];
#pragma unroll
        for (int off = 32; off; off >>= 1) sv += __shfl_xor(sv, off);
        if (lane == 0) out[(size_t)wid * 12 + tsk] = sv + bm2[tsk];
    }
}

// ---------- launch ----------
extern "C" void kernel_launch(void* const* d_in, const int* in_sizes, int n_in,
                              void* d_out, int out_size, void* d_ws, size_t ws_size,
                              hipStream_t stream) {
    const float* atom_output = (const float*)d_in[0];
    const float* f_atoms     = (const float*)d_in[1];
    const int*   a2a         = (const int*)d_in[2];
    const int*   a_scope     = (const int*)d_in[3];
    const float* feats       = (const float*)d_in[4];
    const float* W1  = (const float*)d_in[5];
    const float* b1  = (const float*)d_in[6];
    const float* W2  = (const float*)d_in[7];
    const float* b2  = (const float*)d_in[8];
    const float* ln_g = (const float*)d_in[9];
    const float* ln_b = (const float*)d_in[10];
    const float* Wm1 = (const float*)d_in[11];
    const float* bm1 = (const float*)d_in[12];
    const float* Wm2 = (const float*)d_in[13];
    const float* bm2 = (const float*)d_in[14];
    float* out = (float*)d_out;

    char* ws = (char*)d_ws;
    size_t off = 0;
    auto alloc = [&](size_t bytes) {
        void* p = ws + off;
        off += (bytes + 255) & ~(size_t)255;
        return p;
    };
    unsigned short* h     = (unsigned short*)alloc((size_t)100096 * 256 * 2);  // 51.2 MB
    unsigned short* h1    = (unsigned short*)alloc((size_t)25088 * 1024 * 2);  // 51.4 MB (chunk)
    unsigned short* mol   = (unsigned short*)alloc((size_t)2560 * 512 * 2);
    unsigned short* m1b   = (unsigned short*)alloc((size_t)2560 * 1024 * 2);
    unsigned short* W1bT  = (unsigned short*)alloc((size_t)1024 * 448 * 2);
    unsigned short* W2bT  = (unsigned short*)alloc((size_t)256 * 1024 * 2);
    unsigned short* Wm1bT = (unsigned short*)alloc((size_t)1024 * 512 * 2);

    // weight prep: f32 [R][Cn] -> bf16 [Cn][Kp], K zero-padded
    transpose_pad<<<dim3(14, 32), dim3(32, 8), 0, stream>>>(W1, W1bT, 407, 1024, 448);
    transpose_pad<<<dim3(32, 8),  dim3(32, 8), 0, stream>>>(W2, W2bT, 1024, 256, 1024);
    transpose_pad<<<dim3(16, 32), dim3(32, 8), 0, stream>>>(Wm1, Wm1bT, 456, 1024, 512);

    const int row0s[4] = {0, 25088, 50176, 75264};
    const int nbs[4]   = {196, 196, 196, 194};

    size_t need_full = off + ((size_t)100096 * 448 * 2 + 256) + ((size_t)100000 * 256 * 2 + 256) + (1 << 20);
    if (ws_size >= need_full) {
        // full path: bf16 atom copy + one-shot gather into full x
        unsigned short* xf  = (unsigned short*)alloc((size_t)100096 * 448 * 2);  // 89.7 MB
        unsigned short* abf = (unsigned short*)alloc((size_t)100000 * 256 * 2);  // 51.2 MB
        to_bf16<<<12500, 256, 0, stream>>>(atom_output, abf, (size_t)100000 * 256);
        gather_concat<unsigned short><<<100096, 256, 0, stream>>>(abf, f_atoms, a2a, xf, 0, 100000);
        for (int c = 0; c < 4; c++) {
            int row0 = row0s[c], nb = nbs[c];
            gemm_bt<1><<<nb * 8, 256, 0, stream>>>(xf + (size_t)row0 * 448, W1bT, b1, h1, 8, 1024, 448);
            gemm_bt<0><<<nb * 2, 256, 0, stream>>>(h1, W2bT, b2, h + (size_t)row0 * 256, 2, 256, 1024);
        }
    } else {
        // fallback: chunked f32 gather (fits ~136 MB)
        unsigned short* xbc = (unsigned short*)alloc((size_t)25088 * 448 * 2);
        for (int c = 0; c < 4; c++) {
            int row0 = row0s[c], nb = nbs[c];
            gather_concat<float><<<nb * 128, 256, 0, stream>>>(atom_output, f_atoms, a2a, xbc, row0, 100000);
            gemm_bt<1><<<nb * 8, 256, 0, stream>>>(xbc, W1bT, b1, h1, 8, 1024, 448);
            gemm_bt<0><<<nb * 2, 256, 0, stream>>>(h1, W2bT, b2, h + (size_t)row0 * 256, 2, 256, 1024);
        }
    }

    seg_ln_mean<<<2560, 512, 0, stream>>>(h, a_scope, ln_g, ln_b, feats, mol, 2500);
    // m1 = relu(mol @ Wm1 + bm1) : M=2560, N=1024, K=512
    gemm_bt<1><<<160, 256, 0, stream>>>(mol, Wm1bT, bm1, m1b, 8, 1024, 512);
    ffn2<<<625, 256, 0, stream>>>(m1b, Wm2, bm2, out, 2500);
}

// Round 3
// 467.819 us; speedup vs baseline: 1.2367x; 1.0911x over previous
//
#include <hip/hip_runtime.h>

// ---------- types / helpers ----------
typedef __attribute__((ext_vector_type(8))) short bfrag;   // 8 bf16 (4 VGPRs) MFMA operand
typedef __attribute__((ext_vector_type(4))) float f32x4;   // MFMA accumulator

__device__ __forceinline__ float bf2f(unsigned short u) {
    union { unsigned u32; float f; } cv; cv.u32 = ((unsigned)u) << 16; return cv.f;
}
__device__ __forceinline__ unsigned short f2bf(float f) {
    union { float f; unsigned u; } cv; cv.f = f;
    unsigned u = cv.u;
    unsigned r = (u + 0x7fffu + ((u >> 16) & 1u)) >> 16;   // round-to-nearest-even
    return (unsigned short)r;
}
__device__ __forceinline__ void gll16(const void* g, void* l) {
    __builtin_amdgcn_global_load_lds(
        (const __attribute__((address_space(1))) unsigned int*)g,
        (__attribute__((address_space(3))) unsigned int*)l, 16, 0, 0);
}

// ---------- f32 -> bf16 bulk convert (n multiple of 2048) ----------
__global__ void to_bf16(const float* __restrict__ src, unsigned short* __restrict__ dst, size_t n) {
    size_t i = ((size_t)blockIdx.x * 256 + threadIdx.x) * 8;
    if (i >= n) return;
    float4 a = *reinterpret_cast<const float4*>(src + i);
    float4 b = *reinterpret_cast<const float4*>(src + i + 4);
    ushort4 o0 = {f2bf(a.x), f2bf(a.y), f2bf(a.z), f2bf(a.w)};
    ushort4 o1 = {f2bf(b.x), f2bf(b.y), f2bf(b.z), f2bf(b.w)};
    *reinterpret_cast<ushort4*>(dst + i) = o0;
    *reinterpret_cast<ushort4*>(dst + i + 4) = o1;
}

// ---------- weight transpose + pad + bf16 convert with K-permutation ----------
// W[R][Cn] f32 -> WT[Cn][Kp] bf16 ; K index kn(r) = r<split ? r+shiftA : (r<split2 ? r+shiftB : r)
__global__ void transpose_pad(const float* __restrict__ W, unsigned short* __restrict__ WT,
                              int R, int Cn, int Kp, int split, int shiftA, int split2, int shiftB) {
    __shared__ unsigned short tile[32][33];
    int r0 = blockIdx.x * 32, c0 = blockIdx.y * 32;
#pragma unroll
    for (int j = 0; j < 4; j++) {
        int r = r0 + threadIdx.y + j * 8;
        int c = c0 + threadIdx.x;
        float v = (r < R) ? W[(size_t)r * Cn + c] : 0.f;
        tile[threadIdx.y + j * 8][threadIdx.x] = f2bf(v);
    }
    __syncthreads();
#pragma unroll
    for (int j = 0; j < 4; j++) {
        int c = c0 + threadIdx.y + j * 8;
        int r = r0 + threadIdx.x;
        int kn = (r < split) ? r + shiftA : (r < split2 ? r + shiftB : r);
        WT[(size_t)c * Kp + kn] = tile[threadIdx.x][threadIdx.y + j * 8];
    }
}

// ---------- gather-sum + concat, wave-per-row: x = [aggr(256) | f_atoms(151) | pad(41)] ----------
__global__ __launch_bounds__(256) void gather2(const unsigned short* __restrict__ abf,
                                               const float* __restrict__ f_atoms,
                                               const int* __restrict__ a2a,
                                               unsigned short* __restrict__ xb, int n_real) {
    int r = blockIdx.x * 4 + (threadIdx.x >> 6);
    int lane = threadIdx.x & 63;
    unsigned short* xrow = xb + (size_t)r * 448;
    if (r >= n_real) {
        // zero the padded row (448 cols): 64 lanes x ushort4 covers 256; +48 lanes for rest
        *reinterpret_cast<ushort4*>(xrow + lane * 4) = ushort4{0, 0, 0, 0};
        if (lane < 48) *reinterpret_cast<ushort4*>(xrow + 256 + lane * 4) = ushort4{0, 0, 0, 0};
        return;
    }
    int v = (lane < 10) ? a2a[(size_t)r * 10 + lane] : 0;
    ushort4 u[10];
#pragma unroll
    for (int j = 0; j < 10; j++) {
        int nbj = __shfl(v, j);
        u[j] = *reinterpret_cast<const ushort4*>(abf + (size_t)nbj * 256 + lane * 4);
    }
    float a0 = 0.f, a1 = 0.f, a2 = 0.f, a3 = 0.f;
#pragma unroll
    for (int j = 0; j < 10; j++) {
        a0 += bf2f(u[j].x);
        a1 += bf2f(u[j].y);
        a2 += bf2f(u[j].z);
        a3 += bf2f(u[j].w);
    }
    ushort4 o = {f2bf(a0), f2bf(a1), f2bf(a2), f2bf(a3)};
    *reinterpret_cast<ushort4*>(xrow + lane * 4) = o;   // aggr -> cols 0..255 (aligned)
    // f_atoms -> cols 256..406
    const float* fr = f_atoms + (size_t)r * 151;
#pragma unroll
    for (int s = 0; s < 3; s++) {
        int c = lane + s * 64;
        if (c < 151) xrow[256 + c] = f2bf(fr[c]);
    }
    if (lane < 41) xrow[407 + lane] = 0;   // pad
}

// ---------- bf16 MFMA GEMM, B given transposed:  C[M][N] = A[M][K] * BT[N][K]^T (+bias, relu) ----------
// 128x128 tile, BK=64, 4 waves (2x2). 1-D grid = MB*NB blocks, XCD-swizzled, N-block fastest.
template <int RELU>
__global__ __launch_bounds__(256) void gemm_bt(const unsigned short* __restrict__ A,
                                               const unsigned short* __restrict__ BT,
                                               const float* __restrict__ bias,
                                               unsigned short* __restrict__ C,
                                               int NB, int N, int K) {
    __shared__ __align__(16) unsigned short As[128 * 64];
    __shared__ __align__(16) unsigned short Bs[128 * 64];
    const int t = threadIdx.x;
    const int lane = t & 63, w = t >> 6;
    const int wr = w >> 1, wc = w & 1;

    // bijective XCD swizzle (m204): contiguous wgid chunk per XCD; N-block fastest.
    const int nwg = gridDim.x;
    const int orig = blockIdx.x;
    const int q = nwg >> 3, r8 = nwg & 7;
    const int xcd = orig & 7, slot = orig >> 3;
    const int wgid = (xcd < r8 ? xcd * (q + 1) : r8 * (q + 1) + (xcd - r8) * q) + slot;
    const int bm = (wgid / NB) * 128, bn = (wgid % NB) * 128;

    f32x4 acc[4][4] = {};

    const unsigned short* Ag = A + (size_t)(bm + (t >> 3)) * K + (t & 7) * 8;
    const unsigned short* Bg = BT + (size_t)(bn + (t >> 3)) * K + (t & 7) * 8;
    unsigned short* Al = &As[t * 8];
    unsigned short* Bl = &Bs[t * 8];

    const int la = lane & 15, lb = (lane >> 4) * 8;

    for (int k0 = 0; k0 < K; k0 += 64) {
        __syncthreads();   // previous compute done before overwriting LDS
#pragma unroll
        for (int p = 0; p < 4; p++) gll16(Ag + (size_t)(p * 32) * K + k0, Al + p * 2048);
#pragma unroll
        for (int p = 0; p < 4; p++) gll16(Bg + (size_t)(p * 32) * K + k0, Bl + p * 2048);
        asm volatile("s_waitcnt vmcnt(0)" ::: "memory");
        __syncthreads();
#pragma unroll
        for (int kk = 0; kk < 2; kk++) {
            bfrag a[4], b[4];
#pragma unroll
            for (int i = 0; i < 4; i++)
                a[i] = *reinterpret_cast<const bfrag*>(&As[(wr * 64 + i * 16 + la) * 64 + kk * 32 + lb]);
#pragma unroll
            for (int i = 0; i < 4; i++)
                b[i] = *reinterpret_cast<const bfrag*>(&Bs[(wc * 64 + i * 16 + la) * 64 + kk * 32 + lb]);
#pragma unroll
            for (int i = 0; i < 4; i++)
#pragma unroll
                for (int j = 0; j < 4; j++)
                    acc[i][j] = __builtin_amdgcn_mfma_f32_16x16x32_bf16(a[i], b[j], acc[i][j], 0, 0, 0);
        }
    }

#pragma unroll
    for (int j = 0; j < 4; j++) {
        int col = bn + wc * 64 + j * 16 + la;
        float bv = bias[col];
#pragma unroll
        for (int i = 0; i < 4; i++) {
            int rbase = bm + wr * 64 + i * 16 + (lane >> 4) * 4;
#pragma unroll
            for (int r = 0; r < 4; r++) {
                float v = acc[i][j][r] + bv;
                if (RELU) v = fmaxf(v, 0.f);
                C[(size_t)(rbase + r) * N + col] = f2bf(v);
            }
        }
    }
}

// ---------- fused LayerNorm + segment-mean + feature concat ----------
__global__ __launch_bounds__(512) void seg_ln_mean(const unsigned short* __restrict__ h,
                                                   const int* __restrict__ a_scope,
                                                   const float* __restrict__ g,
                                                   const float* __restrict__ b,
                                                   const float* __restrict__ feats,
                                                   unsigned short* __restrict__ mol, int n_mols) {
    __shared__ float part[8][256];
    int m = blockIdx.x, t = threadIdx.x;
    unsigned short* mrow = mol + (size_t)m * 512;
    if (m >= n_mols) {
        mrow[t] = 0;
        return;
    }
    int w = t >> 6, lane = t & 63;
    int start = a_scope[2 * m], size = a_scope[2 * m + 1];
    float4 gv = *reinterpret_cast<const float4*>(g + lane * 4);
    float4 bv = *reinterpret_cast<const float4*>(b + lane * 4);
    float a0 = 0.f, a1 = 0.f, a2 = 0.f, a3 = 0.f;
    for (int r = w; r < size; r += 8) {
        const unsigned short* hp = h + (size_t)(start + r) * 256 + lane * 4;
        ushort4 u = *reinterpret_cast<const ushort4*>(hp);
        float v0 = bf2f(u.x), v1 = bf2f(u.y), v2 = bf2f(u.z), v3 = bf2f(u.w);
        float s = v0 + v1 + v2 + v3;
        float q2 = v0 * v0 + v1 * v1 + v2 * v2 + v3 * v3;
#pragma unroll
        for (int off = 32; off; off >>= 1) {
            s += __shfl_xor(s, off);
            q2 += __shfl_xor(q2, off);
        }
        float mean = s * (1.f / 256.f);
        float var = q2 * (1.f / 256.f) - mean * mean;
        float rs = rsqrtf(var + 1e-5f);
        a0 += (v0 - mean) * rs * gv.x + bv.x;
        a1 += (v1 - mean) * rs * gv.y + bv.y;
        a2 += (v2 - mean) * rs * gv.z + bv.z;
        a3 += (v3 - mean) * rs * gv.w + bv.w;
    }
    part[w][lane * 4 + 0] = a0;
    part[w][lane * 4 + 1] = a1;
    part[w][lane * 4 + 2] = a2;
    part[w][lane * 4 + 3] = a3;
    __syncthreads();
    if (t < 256) {
        float sum = 0.f;
#pragma unroll
        for (int i = 0; i < 8; i++) sum += part[i][t];
        mrow[t] = f2bf(sum / (float)size);
    } else {
        int c = t - 256;
        float fv = (c < 200) ? feats[(size_t)m * 200 + c] : 0.f;
        mrow[256 + c] = f2bf(fv);
    }
}

// ---------- final tiny FFN layer: out[2500][12] = relu_m1[2500][1024] @ Wm2 + bm2 ----------
__global__ void ffn2(const unsigned short* __restrict__ m1, const float* __restrict__ Wm2,
                     const float* __restrict__ bm2, float* __restrict__ out, int n_mols) {
    int wid = blockIdx.x * 4 + (threadIdx.x >> 6);
    if (wid >= n_mols) return;
    int lane = threadIdx.x & 63;
    float acc[12] = {};
    const unsigned short* row = m1 + (size_t)wid * 1024;
#pragma unroll 4
    for (int i = 0; i < 16; i++) {
        int k = i * 64 + lane;
        float v = bf2f(row[k]);
        const float* wr_ = Wm2 + (size_t)k * 12;
#pragma unroll
        for (int tsk = 0; tsk < 12; tsk++) acc[tsk] += v * wr_[tsk];
    }
#pragma unroll
    for (int tsk = 0; tsk < 12; tsk++) {
        float sv = acc[tsk];
#pragma unroll
        for (int off = 32; off; off >>= 1) sv += __shfl_xor(sv, off);
        if (lane == 0) out[(size_t)wid * 12 + tsk] = sv + bm2[tsk];
    }
}

// ---------- launch ----------
extern "C" void kernel_launch(void* const* d_in, const int* in_sizes, int n_in,
                              void* d_out, int out_size, void* d_ws, size_t ws_size,
                              hipStream_t stream) {
    const float* atom_output = (const float*)d_in[0];
    const float* f_atoms     = (const float*)d_in[1];
    const int*   a2a         = (const int*)d_in[2];
    const int*   a_scope     = (const int*)d_in[3];
    const float* feats       = (const float*)d_in[4];
    const float* W1  = (const float*)d_in[5];
    const float* b1  = (const float*)d_in[6];
    const float* W2  = (const float*)d_in[7];
    const float* b2  = (const float*)d_in[8];
    const float* ln_g = (const float*)d_in[9];
    const float* ln_b = (const float*)d_in[10];
    const float* Wm1 = (const float*)d_in[11];
    const float* bm1 = (const float*)d_in[12];
    const float* Wm2 = (const float*)d_in[13];
    const float* bm2 = (const float*)d_in[14];
    float* out = (float*)d_out;

    char* ws = (char*)d_ws;
    size_t off = 0;
    auto alloc = [&](size_t bytes) {
        void* p = ws + off;
        off += (bytes + 255) & ~(size_t)255;
        return p;
    };
    // total ~305 MB (ws is ~409 MB)
    unsigned short* h     = (unsigned short*)alloc((size_t)100096 * 256 * 2);   // 51.2 MB
    unsigned short* h1    = (unsigned short*)alloc((size_t)50048 * 1024 * 2);   // 102.5 MB (half-chunk)
    unsigned short* xf    = (unsigned short*)alloc((size_t)100096 * 448 * 2);   // 89.7 MB
    unsigned short* abf   = (unsigned short*)alloc((size_t)100000 * 256 * 2);   // 51.2 MB
    unsigned short* mol   = (unsigned short*)alloc((size_t)2560 * 512 * 2);
    unsigned short* m1b   = (unsigned short*)alloc((size_t)2560 * 1024 * 2);
    unsigned short* W1bT  = (unsigned short*)alloc((size_t)1024 * 448 * 2);
    unsigned short* W2bT  = (unsigned short*)alloc((size_t)256 * 1024 * 2);
    unsigned short* Wm1bT = (unsigned short*)alloc((size_t)1024 * 512 * 2);

    // weight prep. W1 gets the K-permutation matching x = [aggr | f_atoms | pad]:
    //   W1 row r<151 (f_atoms weights) -> K 256+r ; 151<=r<407 (aggr weights) -> K r-151 ; r>=407 -> pad
    transpose_pad<<<dim3(14, 32), dim3(32, 8), 0, stream>>>(W1, W1bT, 407, 1024, 448, 151, 256, 407, -151);
    transpose_pad<<<dim3(32, 8),  dim3(32, 8), 0, stream>>>(W2, W2bT, 1024, 256, 1024, 0, 0, 0, 0);
    transpose_pad<<<dim3(16, 32), dim3(32, 8), 0, stream>>>(Wm1, Wm1bT, 456, 1024, 512, 0, 0, 0, 0);

    // bf16 atom pool + one-shot wave-per-row gather
    to_bf16<<<12500, 256, 0, stream>>>(atom_output, abf, (size_t)100000 * 256);
    gather2<<<25024, 256, 0, stream>>>(abf, f_atoms, a2a, xf, 100000);

    // 2 M-chunks of 50048 rows
    for (int c = 0; c < 2; c++) {
        int row0 = c * 50048;
        gemm_bt<1><<<391 * 8, 256, 0, stream>>>(xf + (size_t)row0 * 448, W1bT, b1, h1, 8, 1024, 448);
        gemm_bt<0><<<391 * 2, 256, 0, stream>>>(h1, W2bT, b2, h + (size_t)row0 * 256, 2, 256, 1024);
    }

    seg_ln_mean<<<2560, 512, 0, stream>>>(h, a_scope, ln_g, ln_b, feats, mol, 2500);
    gemm_bt<1><<<160, 256, 0, stream>>>(mol, Wm1bT, bm1, m1b, 8, 1024, 512);
    ffn2<<<625, 256, 0, stream>>>(m1b, Wm2, bm2, out, 2500);
}

// Round 4
// 426.513 us; speedup vs baseline: 1.3565x; 1.0968x over previous
//
#include <hip/hip_runtime.h>

// ---------- types / helpers ----------
typedef __attribute__((ext_vector_type(8))) short bfrag;   // 8 bf16 (4 VGPRs) MFMA operand
typedef __attribute__((ext_vector_type(4))) float f32x4;   // MFMA accumulator

__device__ __forceinline__ float bf2f(unsigned short u) {
    union { unsigned u32; float f; } cv; cv.u32 = ((unsigned)u) << 16; return cv.f;
}
__device__ __forceinline__ unsigned short f2bf(float f) {
    union { float f; unsigned u; } cv; cv.f = f;
    unsigned u = cv.u;
    unsigned r = (u + 0x7fffu + ((u >> 16) & 1u)) >> 16;   // round-to-nearest-even
    return (unsigned short)r;
}
__device__ __forceinline__ void gll16(const void* g, void* l) {
    __builtin_amdgcn_global_load_lds(
        (const __attribute__((address_space(1))) unsigned int*)g,
        (__attribute__((address_space(3))) unsigned int*)l, 16, 0, 0);
}

// ---------- f32 -> bf16 bulk convert (n multiple of 2048) ----------
__global__ void to_bf16(const float* __restrict__ src, unsigned short* __restrict__ dst, size_t n) {
    size_t i = ((size_t)blockIdx.x * 256 + threadIdx.x) * 8;
    if (i >= n) return;
    float4 a = *reinterpret_cast<const float4*>(src + i);
    float4 b = *reinterpret_cast<const float4*>(src + i + 4);
    ushort4 o0 = {f2bf(a.x), f2bf(a.y), f2bf(a.z), f2bf(a.w)};
    ushort4 o1 = {f2bf(b.x), f2bf(b.y), f2bf(b.z), f2bf(b.w)};
    *reinterpret_cast<ushort4*>(dst + i) = o0;
    *reinterpret_cast<ushort4*>(dst + i + 4) = o1;
}

// ---------- weight transpose + pad + bf16 convert with K-permutation ----------
// W[R][Cn] f32 -> WT[Cn][Kp] bf16 ; K index kn(r) = r<split ? r+shiftA : (r<split2 ? r+shiftB : r)
__global__ void transpose_pad(const float* __restrict__ W, unsigned short* __restrict__ WT,
                              int R, int Cn, int Kp, int split, int shiftA, int split2, int shiftB) {
    __shared__ unsigned short tile[32][33];
    int r0 = blockIdx.x * 32, c0 = blockIdx.y * 32;
#pragma unroll
    for (int j = 0; j < 4; j++) {
        int r = r0 + threadIdx.y + j * 8;
        int c = c0 + threadIdx.x;
        float v = (r < R) ? W[(size_t)r * Cn + c] : 0.f;
        tile[threadIdx.y + j * 8][threadIdx.x] = f2bf(v);
    }
    __syncthreads();
#pragma unroll
    for (int j = 0; j < 4; j++) {
        int c = c0 + threadIdx.y + j * 8;
        int r = r0 + threadIdx.x;
        int kn = (r < split) ? r + shiftA : (r < split2 ? r + shiftB : r);
        WT[(size_t)c * Kp + kn] = tile[threadIdx.x][threadIdx.y + j * 8];
    }
}

// ---------- gather-sum + concat, wave-per-row: x = [aggr(256) | f_atoms(151) | pad(41)] ----------
__global__ __launch_bounds__(256) void gather2(const unsigned short* __restrict__ abf,
                                               const float* __restrict__ f_atoms,
                                               const int* __restrict__ a2a,
                                               unsigned short* __restrict__ xb, int n_real) {
    int r = blockIdx.x * 4 + (threadIdx.x >> 6);
    int lane = threadIdx.x & 63;
    unsigned short* xrow = xb + (size_t)r * 448;
    if (r >= n_real) {
        *reinterpret_cast<ushort4*>(xrow + lane * 4) = ushort4{0, 0, 0, 0};
        if (lane < 48) *reinterpret_cast<ushort4*>(xrow + 256 + lane * 4) = ushort4{0, 0, 0, 0};
        return;
    }
    int v = (lane < 10) ? a2a[(size_t)r * 10 + lane] : 0;
    ushort4 u[10];
#pragma unroll
    for (int j = 0; j < 10; j++) {
        int nbj = __shfl(v, j);
        u[j] = *reinterpret_cast<const ushort4*>(abf + (size_t)nbj * 256 + lane * 4);
    }
    float a0 = 0.f, a1 = 0.f, a2 = 0.f, a3 = 0.f;
#pragma unroll
    for (int j = 0; j < 10; j++) {
        a0 += bf2f(u[j].x);
        a1 += bf2f(u[j].y);
        a2 += bf2f(u[j].z);
        a3 += bf2f(u[j].w);
    }
    ushort4 o = {f2bf(a0), f2bf(a1), f2bf(a2), f2bf(a3)};
    *reinterpret_cast<ushort4*>(xrow + lane * 4) = o;   // aggr -> cols 0..255 (aligned)
    const float* fr = f_atoms + (size_t)r * 151;
#pragma unroll
    for (int s = 0; s < 3; s++) {
        int c = lane + s * 64;
        if (c < 151) xrow[256 + c] = f2bf(fr[c]);
    }
    if (lane < 41) xrow[407 + lane] = 0;   // pad
}

// ---------- bf16 MFMA GEMM, B given transposed:  C[M][N] = A[M][K] * BT[N][K]^T (+bias, relu) ----------
// 128x128 tile, BK=64, 4 waves (2x2). Double-buffered LDS, counted vmcnt, raw s_barrier
// (T3-minimum overlap). LDS slot<->row XOR swizzle via pre-swizzled global source (rule #21).
template <int RELU>
__global__ __launch_bounds__(256) void gemm_bt(const unsigned short* __restrict__ A,
                                               const unsigned short* __restrict__ BT,
                                               const float* __restrict__ bias,
                                               unsigned short* __restrict__ C,
                                               int NB, int N, int K) {
    __shared__ __align__(16) unsigned short As[2][128 * 64];
    __shared__ __align__(16) unsigned short Bs[2][128 * 64];
    const int t = threadIdx.x;
    const int lane = t & 63, w = t >> 6;
    const int wr = w >> 1, wc = w & 1;

    // bijective XCD swizzle (m204): contiguous wgid chunk per XCD; N-block fastest.
    const int nwg = gridDim.x;
    const int orig = blockIdx.x;
    const int q = nwg >> 3, r8 = nwg & 7;
    const int xcd = orig & 7, slot = orig >> 3;
    const int wgid = (xcd < r8 ? xcd * (q + 1) : r8 * (q + 1) + (xcd - r8) * q) + slot;
    const int bm = (wgid / NB) * 128, bn = (wgid % NB) * 128;

    f32x4 acc[4][4] = {};

    // staging: thread t owns LDS row trow = t>>3, 16B slot (t&7) (linear dest for gll16).
    // source is pre-swizzled: logical slot = (t&7) ^ (trow&7)  (involution, row-stripe of 8)
    const int trow = t >> 3;
    const int tsl8 = (((t & 7) ^ (trow & 7))) * 8;
    const unsigned short* Ag = A + (size_t)(bm + trow) * K + tsl8;
    const unsigned short* Bg = BT + (size_t)(bn + trow) * K + tsl8;

    const int la = lane & 15, hi = lane >> 4;

    auto stage = [&](int buf, int kk0) {
#pragma unroll
        for (int p = 0; p < 4; p++) gll16(Ag + (size_t)(p * 32) * K + kk0, &As[buf][t * 8 + p * 2048]);
#pragma unroll
        for (int p = 0; p < 4; p++) gll16(Bg + (size_t)(p * 32) * K + kk0, &Bs[buf][t * 8 + p * 2048]);
    };

    stage(0, 0);                    // prologue prefetch, 8 loads in flight
    int cur = 0;
    for (int k0 = 0; k0 < K; k0 += 64) {
        // A: all waves done READING buf[cur^1] (they consumed it via MFMA last iter)
        __builtin_amdgcn_s_barrier();
        if (k0 + 64 < K) {
            stage(cur ^ 1, k0 + 64);                          // 16 outstanding now
            asm volatile("s_waitcnt vmcnt(8)" ::: "memory");  // wait stage(t) only; t+1 stays in flight
        } else {
            asm volatile("s_waitcnt vmcnt(0)" ::: "memory");
        }
        // B: every wave passed its own vmcnt -> stage(t) fully landed in LDS
        __builtin_amdgcn_s_barrier();

        const unsigned short* Ab = &As[cur][0];
        const unsigned short* Bb = &Bs[cur][0];
#pragma unroll
        for (int kk = 0; kk < 2; kk++) {
            const int sl = kk * 4 + hi;   // logical 16B slot within row
            bfrag a[4], b[4];
#pragma unroll
            for (int i = 0; i < 4; i++) {
                int row = wr * 64 + i * 16 + la;
                a[i] = *reinterpret_cast<const bfrag*>(&Ab[row * 64 + ((sl ^ (la & 7)) * 8)]);
            }
#pragma unroll
            for (int i = 0; i < 4; i++) {
                int row = wc * 64 + i * 16 + la;
                b[i] = *reinterpret_cast<const bfrag*>(&Bb[row * 64 + ((sl ^ (la & 7)) * 8)]);
            }
#pragma unroll
            for (int i = 0; i < 4; i++)
#pragma unroll
                for (int j = 0; j < 4; j++)
                    acc[i][j] = __builtin_amdgcn_mfma_f32_16x16x32_bf16(a[i], b[j], acc[i][j], 0, 0, 0);
        }
        cur ^= 1;
    }

#pragma unroll
    for (int j = 0; j < 4; j++) {
        int col = bn + wc * 64 + j * 16 + la;
        float bv = bias[col];
#pragma unroll
        for (int i = 0; i < 4; i++) {
            int rbase = bm + wr * 64 + i * 16 + hi * 4;
#pragma unroll
            for (int r = 0; r < 4; r++) {
                float v = acc[i][j][r] + bv;
                if (RELU) v = fmaxf(v, 0.f);
                C[(size_t)(rbase + r) * N + col] = f2bf(v);
            }
        }
    }
}

// ---------- fused LayerNorm + segment-mean + feature concat ----------
__global__ __launch_bounds__(512) void seg_ln_mean(const unsigned short* __restrict__ h,
                                                   const int* __restrict__ a_scope,
                                                   const float* __restrict__ g,
                                                   const float* __restrict__ b,
                                                   const float* __restrict__ feats,
                                                   unsigned short* __restrict__ mol, int n_mols) {
    __shared__ float part[8][256];
    int m = blockIdx.x, t = threadIdx.x;
    unsigned short* mrow = mol + (size_t)m * 512;
    if (m >= n_mols) {
        mrow[t] = 0;
        return;
    }
    int w = t >> 6, lane = t & 63;
    int start = a_scope[2 * m], size = a_scope[2 * m + 1];
    float4 gv = *reinterpret_cast<const float4*>(g + lane * 4);
    float4 bv = *reinterpret_cast<const float4*>(b + lane * 4);
    float a0 = 0.f, a1 = 0.f, a2 = 0.f, a3 = 0.f;
    for (int r = w; r < size; r += 8) {
        const unsigned short* hp = h + (size_t)(start + r) * 256 + lane * 4;
        ushort4 u = *reinterpret_cast<const ushort4*>(hp);
        float v0 = bf2f(u.x), v1 = bf2f(u.y), v2 = bf2f(u.z), v3 = bf2f(u.w);
        float s = v0 + v1 + v2 + v3;
        float q2 = v0 * v0 + v1 * v1 + v2 * v2 + v3 * v3;
#pragma unroll
        for (int off = 32; off; off >>= 1) {
            s += __shfl_xor(s, off);
            q2 += __shfl_xor(q2, off);
        }
        float mean = s * (1.f / 256.f);
        float var = q2 * (1.f / 256.f) - mean * mean;
        float rs = rsqrtf(var + 1e-5f);
        a0 += (v0 - mean) * rs * gv.x + bv.x;
        a1 += (v1 - mean) * rs * gv.y + bv.y;
        a2 += (v2 - mean) * rs * gv.z + bv.z;
        a3 += (v3 - mean) * rs * gv.w + bv.w;
    }
    part[w][lane * 4 + 0] = a0;
    part[w][lane * 4 + 1] = a1;
    part[w][lane * 4 + 2] = a2;
    part[w][lane * 4 + 3] = a3;
    __syncthreads();
    if (t < 256) {
        float sum = 0.f;
#pragma unroll
        for (int i = 0; i < 8; i++) sum += part[i][t];
        mrow[t] = f2bf(sum / (float)size);
    } else {
        int c = t - 256;
        float fv = (c < 200) ? feats[(size_t)m * 200 + c] : 0.f;
        mrow[256 + c] = f2bf(fv);
    }
}

// ---------- final tiny FFN layer: out[2500][12] = relu_m1[2500][1024] @ Wm2 + bm2 ----------
__global__ void ffn2(const unsigned short* __restrict__ m1, const float* __restrict__ Wm2,
                     const float* __restrict__ bm2, float* __restrict__ out, int n_mols) {
    int wid = blockIdx.x * 4 + (threadIdx.x >> 6);
    if (wid >= n_mols) return;
    int lane = threadIdx.x & 63;
    float acc[12] = {};
    const unsigned short* row = m1 + (size_t)wid * 1024;
#pragma unroll 4
    for (int i = 0; i < 16; i++) {
        int k = i * 64 + lane;
        float v = bf2f(row[k]);
        const float* wr_ = Wm2 + (size_t)k * 12;
#pragma unroll
        for (int tsk = 0; tsk < 12; tsk++) acc[tsk] += v * wr_[tsk];
    }
#pragma unroll
    for (int tsk = 0; tsk < 12; tsk++) {
        float sv = acc[tsk];
#pragma unroll
        for (int off = 32; off; off >>= 1) sv += __shfl_xor(sv, off);
        if (lane == 0) out[(size_t)wid * 12 + tsk] = sv + bm2[tsk];
    }
}

// ---------- launch ----------
extern "C" void kernel_launch(void* const* d_in, const int* in_sizes, int n_in,
                              void* d_out, int out_size, void* d_ws, size_t ws_size,
                              hipStream_t stream) {
    const float* atom_output = (const float*)d_in[0];
    const float* f_atoms     = (const float*)d_in[1];
    const int*   a2a         = (const int*)d_in[2];
    const int*   a_scope     = (const int*)d_in[3];
    const float* feats       = (const float*)d_in[4];
    const float* W1  = (const float*)d_in[5];
    const float* b1  = (const float*)d_in[6];
    const float* W2  = (const float*)d_in[7];
    const float* b2  = (const float*)d_in[8];
    const float* ln_g = (const float*)d_in[9];
    const float* ln_b = (const float*)d_in[10];
    const float* Wm1 = (const float*)d_in[11];
    const float* bm1 = (const float*)d_in[12];
    const float* Wm2 = (const float*)d_in[13];
    const float* bm2 = (const float*)d_in[14];
    float* out = (float*)d_out;

    char* ws = (char*)d_ws;
    size_t off = 0;
    auto alloc = [&](size_t bytes) {
        void* p = ws + off;
        off += (bytes + 255) & ~(size_t)255;
        return p;
    };
    // total ~305 MB (ws is ~409 MB)
    unsigned short* h     = (unsigned short*)alloc((size_t)100096 * 256 * 2);   // 51.2 MB
    unsigned short* h1    = (unsigned short*)alloc((size_t)50048 * 1024 * 2);   // 102.5 MB (half-chunk)
    unsigned short* xf    = (unsigned short*)alloc((size_t)100096 * 448 * 2);   // 89.7 MB
    unsigned short* abf   = (unsigned short*)alloc((size_t)100000 * 256 * 2);   // 51.2 MB
    unsigned short* mol   = (unsigned short*)alloc((size_t)2560 * 512 * 2);
    unsigned short* m1b   = (unsigned short*)alloc((size_t)2560 * 1024 * 2);
    unsigned short* W1bT  = (unsigned short*)alloc((size_t)1024 * 448 * 2);
    unsigned short* W2bT  = (unsigned short*)alloc((size_t)256 * 1024 * 2);
    unsigned short* Wm1bT = (unsigned short*)alloc((size_t)1024 * 512 * 2);

    // weight prep. W1 gets the K-permutation matching x = [aggr | f_atoms | pad]:
    //   W1 row r<151 (f_atoms weights) -> K 256+r ; 151<=r<407 (aggr weights) -> K r-151 ; r>=407 -> pad
    transpose_pad<<<dim3(14, 32), dim3(32, 8), 0, stream>>>(W1, W1bT, 407, 1024, 448, 151, 256, 407, -151);
    transpose_pad<<<dim3(32, 8),  dim3(32, 8), 0, stream>>>(W2, W2bT, 1024, 256, 1024, 0, 0, 0, 0);
    transpose_pad<<<dim3(16, 32), dim3(32, 8), 0, stream>>>(Wm1, Wm1bT, 456, 1024, 512, 0, 0, 0, 0);

    // bf16 atom pool + one-shot wave-per-row gather
    to_bf16<<<12500, 256, 0, stream>>>(atom_output, abf, (size_t)100000 * 256);
    gather2<<<25024, 256, 0, stream>>>(abf, f_atoms, a2a, xf, 100000);

    // 2 M-chunks of 50048 rows
    for (int c = 0; c < 2; c++) {
        int row0 = c * 50048;
        gemm_bt<1><<<391 * 8, 256, 0, stream>>>(xf + (size_t)row0 * 448, W1bT, b1, h1, 8, 1024, 448);
        gemm_bt<0><<<391 * 2, 256, 0, stream>>>(h1, W2bT, b2, h + (size_t)row0 * 256, 2, 256, 1024);
    }

    seg_ln_mean<<<2560, 512, 0, stream>>>(h, a_scope, ln_g, ln_b, feats, mol, 2500);
    gemm_bt<1><<<160, 256, 0, stream>>>(mol, Wm1bT, bm1, m1b, 8, 1024, 512);
    ffn2<<<625, 256, 0, stream>>>(m1b, Wm2, bm2, out, 2500);
}

// Round 5
// 425.254 us; speedup vs baseline: 1.3605x; 1.0030x over previous
//
#include <hip/hip_runtime.h>

// ---------- types / helpers ----------
typedef __attribute__((ext_vector_type(8))) short bfrag;   // 8 bf16 (4 VGPRs) MFMA operand
typedef __attribute__((ext_vector_type(4))) float f32x4;   // MFMA accumulator

__device__ __forceinline__ float bf2f(unsigned short u) {
    union { unsigned u32; float f; } cv; cv.u32 = ((unsigned)u) << 16; return cv.f;
}
__device__ __forceinline__ unsigned short f2bf(float f) {
    union { float f; unsigned u; } cv; cv.f = f;
    unsigned u = cv.u;
    unsigned r = (u + 0x7fffu + ((u >> 16) & 1u)) >> 16;   // round-to-nearest-even
    return (unsigned short)r;
}
__device__ __forceinline__ void gll16(const void* g, void* l) {
    __builtin_amdgcn_global_load_lds(
        (const __attribute__((address_space(1))) unsigned int*)g,
        (__attribute__((address_space(3))) unsigned int*)l, 16, 0, 0);
}
#define SB  __builtin_amdgcn_sched_barrier(0)
#define BAR __builtin_amdgcn_s_barrier()

// ---------- f32 -> bf16 bulk convert ----------
__global__ void to_bf16(const float* __restrict__ src, unsigned short* __restrict__ dst, size_t n) {
    size_t i = ((size_t)blockIdx.x * 256 + threadIdx.x) * 8;
    if (i >= n) return;
    float4 a = *reinterpret_cast<const float4*>(src + i);
    float4 b = *reinterpret_cast<const float4*>(src + i + 4);
    ushort4 o0 = {f2bf(a.x), f2bf(a.y), f2bf(a.z), f2bf(a.w)};
    ushort4 o1 = {f2bf(b.x), f2bf(b.y), f2bf(b.z), f2bf(b.w)};
    *reinterpret_cast<ushort4*>(dst + i) = o0;
    *reinterpret_cast<ushort4*>(dst + i + 4) = o1;
}

// ---------- weight transpose + pad + bf16 convert with K-permutation ----------
__global__ void transpose_pad(const float* __restrict__ W, unsigned short* __restrict__ WT,
                              int R, int Cn, int Kp, int split, int shiftA, int split2, int shiftB) {
    __shared__ unsigned short tile[32][33];
    int r0 = blockIdx.x * 32, c0 = blockIdx.y * 32;
#pragma unroll
    for (int j = 0; j < 4; j++) {
        int r = r0 + threadIdx.y + j * 8;
        int c = c0 + threadIdx.x;
        float v = (r < R) ? W[(size_t)r * Cn + c] : 0.f;
        tile[threadIdx.y + j * 8][threadIdx.x] = f2bf(v);
    }
    __syncthreads();
#pragma unroll
    for (int j = 0; j < 4; j++) {
        int c = c0 + threadIdx.y + j * 8;
        int r = r0 + threadIdx.x;
        int kn = (r < split) ? r + shiftA : (r < split2 ? r + shiftB : r);
        WT[(size_t)c * Kp + kn] = tile[threadIdx.x][threadIdx.y + j * 8];
    }
}

// ---------- gather-sum + concat, wave-per-row: x = [aggr(256) | f_atoms(151) | pad(41)] ----------
__global__ __launch_bounds__(256) void gather2(const unsigned short* __restrict__ abf,
                                               const float* __restrict__ f_atoms,
                                               const int* __restrict__ a2a,
                                               unsigned short* __restrict__ xb, int n_real) {
    int r = blockIdx.x * 4 + (threadIdx.x >> 6);
    int lane = threadIdx.x & 63;
    unsigned short* xrow = xb + (size_t)r * 448;
    if (r >= n_real) {
        *reinterpret_cast<ushort4*>(xrow + lane * 4) = ushort4{0, 0, 0, 0};
        if (lane < 48) *reinterpret_cast<ushort4*>(xrow + 256 + lane * 4) = ushort4{0, 0, 0, 0};
        return;
    }
    int v = (lane < 10) ? a2a[(size_t)r * 10 + lane] : 0;
    ushort4 u[10];
#pragma unroll
    for (int j = 0; j < 10; j++) {
        int nbj = __shfl(v, j);
        u[j] = *reinterpret_cast<const ushort4*>(abf + (size_t)nbj * 256 + lane * 4);
    }
    float a0 = 0.f, a1 = 0.f, a2 = 0.f, a3 = 0.f;
#pragma unroll
    for (int j = 0; j < 10; j++) {
        a0 += bf2f(u[j].x);
        a1 += bf2f(u[j].y);
        a2 += bf2f(u[j].z);
        a3 += bf2f(u[j].w);
    }
    ushort4 o = {f2bf(a0), f2bf(a1), f2bf(a2), f2bf(a3)};
    *reinterpret_cast<ushort4*>(xrow + lane * 4) = o;
    const float* fr = f_atoms + (size_t)r * 151;
#pragma unroll
    for (int s = 0; s < 3; s++) {
        int c = lane + s * 64;
        if (c < 151) xrow[256 + c] = f2bf(fr[c]);
    }
    if (lane < 41) xrow[407 + lane] = 0;
}

// ---------- 256x256 8-phase bf16 MFMA GEMM (B transposed): C = A[M][K] * BT[N][K]^T (+bias, relu)
// 8 waves (2M x 4N), wave tile 128x64 interleaved across LDS halves; BK=64, double-buffered,
// per-phase {ds_read || gll16-stage || barrier || setprio MFMA}, one counted vmcnt per K-tile.
template <int RELU>
__global__ __launch_bounds__(512, 2) void gemm256(const unsigned short* __restrict__ A,
                                                  const unsigned short* __restrict__ BT,
                                                  const float* __restrict__ bias,
                                                  unsigned short* __restrict__ C,
                                                  int NB, int N, int K) {
    __shared__ __align__(16) unsigned short As[2][16384];   // 2 x 256x64 bf16 = 64 KB
    __shared__ __align__(16) unsigned short Bs[2][16384];   // 64 KB
    const int t = threadIdx.x;
    const int lane = t & 63, wid = t >> 6;
    const int wr = wid >> 2, wc = wid & 3;
    const int la = lane & 15, hi = lane >> 4;

    // bijective XCD swizzle (m204), N-block fastest
    const int nwg = gridDim.x, orig = blockIdx.x;
    const int q = nwg >> 3, r8 = nwg & 7;
    const int xcd = orig & 7, slot = orig >> 3;
    const int wgid = (xcd < r8 ? xcd * (q + 1) : r8 * (q + 1) + (xcd - r8) * q) + slot;
    const int bm = (wgid / NB) * 256, bn = (wgid % NB) * 256;

    // staging: thread t -> 64-row group row trow, 16B slot tslot (linear LDS dest);
    // global source pre-swizzled: logical slot = tslot ^ (trow&7)  (involution per 8-row stripe)
    const int trow = t >> 3, tslot = t & 7;
    const int tsrc = (tslot ^ (trow & 7)) * 8;
    const unsigned short* Ag = A + (size_t)(bm + trow) * K + tsrc;
    const unsigned short* Bg = BT + (size_t)(bn + trow) * K + tsrc;
    const int ldst = trow * 64 + tslot * 8;

    const int NT = K >> 6;

    auto stageA = [&](int buf, int h, int kt) {
        gll16(Ag + ((size_t)(h * 128) * K + kt * 64), &As[buf][h * 8192 + ldst]);
        gll16(Ag + ((size_t)(h * 128 + 64) * K + kt * 64), &As[buf][h * 8192 + 4096 + ldst]);
    };
    auto stageB = [&](int buf, int h, int kt) {
        gll16(Bg + ((size_t)(h * 128) * K + kt * 64), &Bs[buf][h * 8192 + ldst]);
        gll16(Bg + ((size_t)(h * 128 + 64) * K + kt * 64), &Bs[buf][h * 8192 + 4096 + ldst]);
    };
    // frag reads (phys slot = logical ^ (row&7); row&7 == la&7 here)
    auto rdA = [&](const unsigned short* Ab, int mh, int kk, bfrag* a) {
#pragma unroll
        for (int i = 0; i < 4; i++) {
            int row = wr * 64 + mh * 128 + i * 16 + la;
            a[i] = *reinterpret_cast<const bfrag*>(&Ab[row * 64 + (((kk * 4 + hi) ^ (la & 7)) * 8)]);
        }
    };
    auto rdB = [&](const unsigned short* Bb, int nh, int kk, bfrag* b) {
#pragma unroll
        for (int j = 0; j < 2; j++) {
            int row = wc * 32 + nh * 128 + j * 16 + la;
            b[j] = *reinterpret_cast<const bfrag*>(&Bb[row * 64 + (((kk * 4 + hi) ^ (la & 7)) * 8)]);
        }
    };

    f32x4 acc[8][4] = {};

#define MFMA_Q(mh, nh)                                                                              \
    _Pragma("unroll") for (int i = 0; i < 4; i++) {                                                 \
        _Pragma("unroll") for (int j = 0; j < 2; j++) {                                             \
            acc[(mh)*4 + i][(nh)*2 + j] =                                                           \
                __builtin_amdgcn_mfma_f32_16x16x32_bf16(a0[i], b0[j], acc[(mh)*4 + i][(nh)*2 + j],  \
                                                        0, 0, 0);                                   \
            acc[(mh)*4 + i][(nh)*2 + j] =                                                           \
                __builtin_amdgcn_mfma_f32_16x16x32_bf16(a1[i], b1[j], acc[(mh)*4 + i][(nh)*2 + j],  \
                                                        0, 0, 0);                                   \
        }                                                                                           \
    }

    // prologue: tile0 all halves + tile1 A0; wait tile0 (2 newest may fly)
    stageA(0, 0, 0); stageB(0, 0, 0); stageA(0, 1, 0); stageB(0, 1, 0);
    if (NT > 1) stageA(1, 0, 1);
    SB;
    if (NT > 1) asm volatile("s_waitcnt vmcnt(2)" ::: "memory");
    else        asm volatile("s_waitcnt vmcnt(0)" ::: "memory");
    SB; BAR; SB;

    int cur = 0;
    for (int kt = 0; kt < NT; kt++) {
        const unsigned short* Ab = &As[cur][0];
        const unsigned short* Bb = &Bs[cur][0];
        const int nxt = cur ^ 1;
        bfrag a0[4], a1[4], b0[2], b1[2];

        // p0 (mh0, nh0) ---- stage B0(t+1)
        rdA(Ab, 0, 0, a0); rdA(Ab, 0, 1, a1);
        rdB(Bb, 0, 0, b0); rdB(Bb, 0, 1, b1);
        if (kt + 1 < NT) stageB(nxt, 0, kt + 1);
        SB; BAR; SB;
        __builtin_amdgcn_s_setprio(1);
        MFMA_Q(0, 0);
        __builtin_amdgcn_s_setprio(0);
        SB; BAR; SB;

        // p1 (mh0, nh1) ---- stage A1(t+1), B1(t+1)
        rdB(Bb, 1, 0, b0); rdB(Bb, 1, 1, b1);
        if (kt + 1 < NT) { stageA(nxt, 1, kt + 1); stageB(nxt, 1, kt + 1); }
        SB; BAR; SB;
        __builtin_amdgcn_s_setprio(1);
        MFMA_Q(0, 1);
        __builtin_amdgcn_s_setprio(0);
        SB; BAR; SB;

        // p2 (mh1, nh0)
        rdA(Ab, 1, 0, a0); rdA(Ab, 1, 1, a1);
        rdB(Bb, 0, 0, b0); rdB(Bb, 0, 1, b1);
        SB; BAR; SB;
        __builtin_amdgcn_s_setprio(1);
        MFMA_Q(1, 0);
        __builtin_amdgcn_s_setprio(0);
        SB; BAR; SB;

        // p3 (mh1, nh1) ---- stage A0(t+2) into cur (A0 dead since p1); counted vmcnt
        rdB(Bb, 1, 0, b0); rdB(Bb, 1, 1, b1);
        if (kt + 2 < NT) stageA(cur, 0, kt + 2);
        SB; BAR; SB;
        __builtin_amdgcn_s_setprio(1);
        MFMA_Q(1, 1);
        __builtin_amdgcn_s_setprio(0);
        SB;
        if (kt + 1 < NT) {
            if (kt + 2 < NT) asm volatile("s_waitcnt vmcnt(2)" ::: "memory");
            else             asm volatile("s_waitcnt vmcnt(0)" ::: "memory");
        }
        SB; BAR; SB;
        cur = nxt;
    }
#undef MFMA_Q

    // epilogue: bias + optional relu, bf16 store
#pragma unroll
    for (int mh = 0; mh < 2; mh++)
#pragma unroll
        for (int i = 0; i < 4; i++) {
            int rbase = bm + wr * 64 + mh * 128 + i * 16 + hi * 4;
#pragma unroll
            for (int nh = 0; nh < 2; nh++)
#pragma unroll
                for (int j = 0; j < 2; j++) {
                    int col = bn + wc * 32 + nh * 128 + j * 16 + la;
                    float bv = bias[col];
                    f32x4 av = acc[mh * 4 + i][nh * 2 + j];
#pragma unroll
                    for (int r = 0; r < 4; r++) {
                        float v = av[r] + bv;
                        if (RELU) v = fmaxf(v, 0.f);
                        C[(size_t)(rbase + r) * N + col] = f2bf(v);
                    }
                }
        }
}

// ---------- fused LayerNorm + segment-mean + feature concat ----------
__global__ __launch_bounds__(512) void seg_ln_mean(const unsigned short* __restrict__ h,
                                                   const int* __restrict__ a_scope,
                                                   const float* __restrict__ g,
                                                   const float* __restrict__ b,
                                                   const float* __restrict__ feats,
                                                   unsigned short* __restrict__ mol, int n_mols) {
    __shared__ float part[8][256];
    int m = blockIdx.x, t = threadIdx.x;
    unsigned short* mrow = mol + (size_t)m * 512;
    if (m >= n_mols) {
        mrow[t] = 0;
        return;
    }
    int w = t >> 6, lane = t & 63;
    int start = a_scope[2 * m], size = a_scope[2 * m + 1];
    float4 gv = *reinterpret_cast<const float4*>(g + lane * 4);
    float4 bv = *reinterpret_cast<const float4*>(b + lane * 4);
    float a0 = 0.f, a1 = 0.f, a2 = 0.f, a3 = 0.f;
    for (int r = w; r < size; r += 8) {
        const unsigned short* hp = h + (size_t)(start + r) * 256 + lane * 4;
        ushort4 u = *reinterpret_cast<const ushort4*>(hp);
        float v0 = bf2f(u.x), v1 = bf2f(u.y), v2 = bf2f(u.z), v3 = bf2f(u.w);
        float s = v0 + v1 + v2 + v3;
        float q2 = v0 * v0 + v1 * v1 + v2 * v2 + v3 * v3;
#pragma unroll
        for (int off = 32; off; off >>= 1) {
            s += __shfl_xor(s, off);
            q2 += __shfl_xor(q2, off);
        }
        float mean = s * (1.f / 256.f);
        float var = q2 * (1.f / 256.f) - mean * mean;
        float rs = rsqrtf(var + 1e-5f);
        a0 += (v0 - mean) * rs * gv.x + bv.x;
        a1 += (v1 - mean) * rs * gv.y + bv.y;
        a2 += (v2 - mean) * rs * gv.z + bv.z;
        a3 += (v3 - mean) * rs * gv.w + bv.w;
    }
    part[w][lane * 4 + 0] = a0;
    part[w][lane * 4 + 1] = a1;
    part[w][lane * 4 + 2] = a2;
    part[w][lane * 4 + 3] = a3;
    __syncthreads();
    if (t < 256) {
        float sum = 0.f;
#pragma unroll
        for (int i = 0; i < 8; i++) sum += part[i][t];
        mrow[t] = f2bf(sum / (float)size);
    } else {
        int c = t - 256;
        float fv = (c < 200) ? feats[(size_t)m * 200 + c] : 0.f;
        mrow[256 + c] = f2bf(fv);
    }
}

// ---------- final tiny FFN layer ----------
__global__ void ffn2(const unsigned short* __restrict__ m1, const float* __restrict__ Wm2,
                     const float* __restrict__ bm2, float* __restrict__ out, int n_mols) {
    int wid = blockIdx.x * 4 + (threadIdx.x >> 6);
    if (wid >= n_mols) return;
    int lane = threadIdx.x & 63;
    float acc[12] = {};
    const unsigned short* row = m1 + (size_t)wid * 1024;
#pragma unroll 4
    for (int i = 0; i < 16; i++) {
        int k = i * 64 + lane;
        float v = bf2f(row[k]);
        const float* wr_ = Wm2 + (size_t)k * 12;
#pragma unroll
        for (int tsk = 0; tsk < 12; tsk++) acc[tsk] += v * wr_[tsk];
    }
#pragma unroll
    for (int tsk = 0; tsk < 12; tsk++) {
        float sv = acc[tsk];
#pragma unroll
        for (int off = 32; off; off >>= 1) sv += __shfl_xor(sv, off);
        if (lane == 0) out[(size_t)wid * 12 + tsk] = sv + bm2[tsk];
    }
}

// ---------- launch ----------
extern "C" void kernel_launch(void* const* d_in, const int* in_sizes, int n_in,
                              void* d_out, int out_size, void* d_ws, size_t ws_size,
                              hipStream_t stream) {
    const float* atom_output = (const float*)d_in[0];
    const float* f_atoms     = (const float*)d_in[1];
    const int*   a2a         = (const int*)d_in[2];
    const int*   a_scope     = (const int*)d_in[3];
    const float* feats       = (const float*)d_in[4];
    const float* W1  = (const float*)d_in[5];
    const float* b1  = (const float*)d_in[6];
    const float* W2  = (const float*)d_in[7];
    const float* b2  = (const float*)d_in[8];
    const float* ln_g = (const float*)d_in[9];
    const float* ln_b = (const float*)d_in[10];
    const float* Wm1 = (const float*)d_in[11];
    const float* bm1 = (const float*)d_in[12];
    const float* Wm2 = (const float*)d_in[13];
    const float* bm2 = (const float*)d_in[14];
    float* out = (float*)d_out;

    char* ws = (char*)d_ws;
    size_t off = 0;
    auto alloc = [&](size_t bytes) {
        void* p = ws + off;
        off += (bytes + 255) & ~(size_t)255;
        return p;
    };
    // ~356 MB total (ws ~409 MB). abf aliases h1 (dead before gemm1 writes h1).
    unsigned short* h     = (unsigned short*)alloc((size_t)100096 * 256 * 2);    // 51.2 MB
    unsigned short* h1    = (unsigned short*)alloc((size_t)100096 * 1024 * 2);   // 205.0 MB
    unsigned short* xf    = (unsigned short*)alloc((size_t)100096 * 448 * 2);    // 89.7 MB
    unsigned short* mol   = (unsigned short*)alloc((size_t)2560 * 512 * 2);
    unsigned short* m1b   = (unsigned short*)alloc((size_t)2560 * 1024 * 2);
    unsigned short* W1bT  = (unsigned short*)alloc((size_t)1024 * 448 * 2);
    unsigned short* W2bT  = (unsigned short*)alloc((size_t)256 * 1024 * 2);
    unsigned short* Wm1bT = (unsigned short*)alloc((size_t)1024 * 512 * 2);
    unsigned short* abf   = h1;   // alias: 51.2 MB, consumed by gather2 before h1 is written

    // weight prep. W1 K-permuted for x = [aggr | f_atoms | pad]
    transpose_pad<<<dim3(14, 32), dim3(32, 8), 0, stream>>>(W1, W1bT, 407, 1024, 448, 151, 256, 407, -151);
    transpose_pad<<<dim3(32, 8),  dim3(32, 8), 0, stream>>>(W2, W2bT, 1024, 256, 1024, 0, 0, 0, 0);
    transpose_pad<<<dim3(16, 32), dim3(32, 8), 0, stream>>>(Wm1, Wm1bT, 456, 1024, 512, 0, 0, 0, 0);

    to_bf16<<<12500, 256, 0, stream>>>(atom_output, abf, (size_t)100000 * 256);
    gather2<<<25024, 256, 0, stream>>>(abf, f_atoms, a2a, xf, 100000);

    // h1 = relu(x @ W1 + b1) : M=100096, N=1024, K=448
    gemm256<1><<<391 * 4, 512, 0, stream>>>(xf, W1bT, b1, h1, 4, 1024, 448);
    // h = h1 @ W2 + b2 : M=100096, N=256, K=1024
    gemm256<0><<<391 * 1, 512, 0, stream>>>(h1, W2bT, b2, h, 1, 256, 1024);

    seg_ln_mean<<<2560, 512, 0, stream>>>(h, a_scope, ln_g, ln_b, feats, mol, 2500);
    // m1 = relu(mol @ Wm1 + bm1) : M=2560, N=1024, K=512
    gemm256<1><<<10 * 4, 512, 0, stream>>>(mol, Wm1bT, bm1, m1b, 4, 1024, 512);
    ffn2<<<625, 256, 0, stream>>>(m1b, Wm2, bm2, out, 2500);
}